// Round 5
// baseline (103.944 us; speedup 1.0000x reference)
//
#include <hip/hip_runtime.h>
#include <hip/hip_fp16.h>
#include <stdint.h>

#define BATCH 128
#define CIN   64
#define NFLOW 16
#define COUT  256
#define HH    20
#define WW    20
#define NPIX  400
#define KTOT  1024
#define PT    80          // pixel tile
#define NPT   5           // tiles per batch
#define NTH   512         // 8 waves, each owns 32 out-rows x all 5 N-frags
#define FLS   72          // f16 per fl row = 144 B
#define XCC   448         // xc cells per plane (400 + pad to 7*64)

typedef __attribute__((ext_vector_type(8))) short sh8;   // MFMA A/B frag (8 f16)
typedef __attribute__((ext_vector_type(4))) float f4;    // MFMA C/D frag

// ---- prep: W fp32 [256][1024] -> f16 MFMA-frag layout over permuted k' ----
// k' = kc*64 + fi*8 + ci ; kc = fb*8 + cb ; f = fb*8+fi, c = cb*8+ci, k = c*16+f.
// Frag layout: Wf[((kc16*16 + mf)*64 + h*16 + lr)*8 + j], k' = kc16*32 + h*8 + j,
// row m = mf*16 + lr.
__global__ void prep_w(const float* __restrict__ wg, __half* __restrict__ Wf) {
    int gid = blockIdx.x * 256 + threadIdx.x;   // [0, 32768)
    int j8  = gid & 127;          // k'-octet 0..127
    int row = gid >> 7;           // 0..255
    int kc16 = j8 >> 2;
    int h    = j8 & 3;
    __half* dst = Wf + ((size_t)(kc16 * 16 + (row >> 4)) * 64 + h * 16 + (row & 15)) * 8;
    #pragma unroll
    for (int j = 0; j < 8; ++j) {
        int kp = j8 * 8 + j;                  // k' in [0,1024)
        int kc = kp >> 6;
        int l  = kp & 63;
        int f  = (kc >> 3) * 8 + (l >> 3);
        int c  = (kc & 7) * 8 + (l & 7);
        dst[j] = __float2half(wg[(size_t)row * KTOT + c * NFLOW + f]);
    }
}

// ---- prep: x fp32 [b][c][pix] -> xt f16 [b][pix][c] (16B per 8-ch slice) ----
__global__ void prep_x(const float* __restrict__ xg, __half* __restrict__ xt) {
    int bid  = blockIdx.x;          // 512 = 128 b x 4 quarters
    int b    = bid >> 2, q = bid & 3;
    int lane = threadIdx.x & 63;    // channel
    int w    = threadIdx.x >> 6;    // 4 waves
    const float* src = xg + (size_t)b * (CIN * NPIX) + (size_t)lane * NPIX;
    __half*      dst = xt + (size_t)b * (NPIX * CIN) + lane;
    int pbeg = q * 100 + w * 25;
    #pragma unroll
    for (int p = pbeg; p < pbeg + 25; ++p)
        dst[(size_t)p * CIN] = __float2half(src[p]);   // 128B coalesced store/wave
}

__global__ __launch_bounds__(NTH, 6) void flow_main(
    const __half* __restrict__ xt, const __half* __restrict__ Wf,
    const float* __restrict__ flowg, const float* __restrict__ biasg,
    float* __restrict__ outg)
{
    // xc: double-buffered 8-channel plane, cell layout [pix*8 + ci] f16 (16B cells)
    __shared__ __align__(16) __half xc[2][XCC * 8];    // 14336 B
    __shared__ __align__(16) __half fl[2][PT * FLS];   // 23040 B   (total 37376 B)

    const int bid0 = blockIdx.x;
    const int bid  = (bid0 & 7) * (BATCH * NPT / 8) + (bid0 >> 3);  // XCD swizzle
    const int b  = bid / NPT;
    const int pt = bid - b * NPT;
    const int p0 = pt * PT;

    const int tid  = threadIdx.x;
    const int wv   = tid >> 6;        // wave owns out-rows [wv*32, wv*32+32), flow fi=wv
    const int lane = tid & 63;
    const int lr   = lane & 15;
    const int lk   = (lane >> 4) * 8;

    const __half* xtb = xt + (size_t)b * (NPIX * CIN);

    // ---- DMA one 8-ch plane (chunk k) into xc[k&1]: 7 global_load_lds x 1KB ----
    auto stage_x = [&](int k) {
        if (wv < 7) {
            const __half* src = xtb + (size_t)(wv * 64 + lane) * CIN + (k & 7) * 8;
            __builtin_amdgcn_global_load_lds(
                (const __attribute__((address_space(1))) void*)src,
                (__attribute__((address_space(3))) void*)&xc[k & 1][wv * 64 * 8],
                16, 0, 0);
        }
    };

    // ---- warp tables: wave wv handles flow fi=wv, pixels p = it*64 + lane ----
    __half2 w2_[2][4];
    int     pb_[2][4];     // corner cell byte offset within plane (pr * 16)
    int     fo_[2];        // fl byte offset = p*144 + wv*16

    auto build_tables = [&](int fb) {
        #pragma unroll
        for (int it = 0; it < 2; ++it) {
            if (it == 0 || lane < 16) {
                int p  = it * 64 + lane;       // [0,80)
                int f  = fb * 8 + wv;
                int gp = p0 + p;
                int i = gp / WW;
                int j = gp - i * WW;
                float fx = flowg[((f * HH + i) * WW + j) * 2 + 0];
                float fy = flowg[((f * HH + i) * WW + j) * 2 + 1];
                float ax = (float)i + fx;
                float ay = (float)j + fy;
                float bxf = floorf(ax), byf = floorf(ay);
                float s = ax - bxf, t = ay - byf;
                int ibx = (int)bxf, iby = (int)byf;
                float w00 = (1.f - s) * (1.f - t);
                float w01 = s * (1.f - t);
                float w10 = s * (1.f - t);        // replicate reference's weight bug
                float w11 = s * t;
                int cx0 = min(max(ibx, 0), HH);
                int cx1 = min(max(ibx + 1, 0), HH);
                int cy0 = min(max(iby, 0), WW);
                int cy1 = min(max(iby + 1, 0), WW);
                int v0 = (cx0 < HH) & (cy0 < WW);
                int v1 = (cx1 < HH) & (cy0 < WW);
                int v2 = (cx0 < HH) & (cy1 < WW);
                int v3 = (cx1 < HH) & (cy1 < WW);
                w2_[it][0] = __half2half2(__float2half(v0 ? w00 : 0.f));
                w2_[it][1] = __half2half2(__float2half(v1 ? w01 : 0.f));
                w2_[it][2] = __half2half2(__float2half(v2 ? w10 : 0.f));
                w2_[it][3] = __half2half2(__float2half(v3 ? w11 : 0.f));
                pb_[it][0] = (v0 ? (cx0 * WW + cy0) : 0) * 16;
                pb_[it][1] = (v1 ? (cx1 * WW + cy0) : 0) * 16;
                pb_[it][2] = (v2 ? (cx0 * WW + cy1) : 0) * 16;
                pb_[it][3] = (v3 ? (cx1 * WW + cy1) : 0) * 16;
                fo_[it] = p * (FLS * 2) + wv * 16;
            }
        }
    };

    // ---- fill chunk k: gather 8 channels of flow fi=wv into fl[k&1] ----
    auto fill = [&](int k) {
        const char* xcb = (const char*)xc[k & 1];
        char* flb = (char*)fl[k & 1];
        #pragma unroll
        for (int it = 0; it < 2; ++it) {
            if (it == 0 || lane < 16) {
                __half2 s0 = __builtin_bit_cast(__half2, 0u);
                __half2 s1 = s0, s2 = s0, s3 = s0;
                #pragma unroll
                for (int q = 0; q < 4; ++q) {
                    const uint4 d = *(const uint4*)(xcb + pb_[it][q]);
                    __half2 wq = w2_[it][q];
                    s0 = __hfma2(wq, __builtin_bit_cast(__half2, d.x), s0);
                    s1 = __hfma2(wq, __builtin_bit_cast(__half2, d.y), s1);
                    s2 = __hfma2(wq, __builtin_bit_cast(__half2, d.z), s2);
                    s3 = __hfma2(wq, __builtin_bit_cast(__half2, d.w), s3);
                }
                uint4 pk;
                pk.x = __builtin_bit_cast(uint32_t, s0);
                pk.y = __builtin_bit_cast(uint32_t, s1);
                pk.z = __builtin_bit_cast(uint32_t, s2);
                pk.w = __builtin_bit_cast(uint32_t, s3);
                *(uint4*)(flb + fo_[it]) = pk;
            }
        }
    };

    // ---- prologue: tables + DMA chunks 0,1; fill(0) ----
    build_tables(0);
    stage_x(0);
    stage_x(1);
    __syncthreads();   // xc[0], xc[1] landed (barrier drains vmcnt)
    fill(0);
    __syncthreads();   // fl[0] ready

    f4 acc[2][5] = {};

    for (int kc = 0; kc < 16; ++kc) {          // chunk = (fb = kc>>3, cb = kc&7)
        if (kc == 7) build_tables(1);          // tables for fb=1 before fill(8)

        // ---- A-frags: 2 M-frags x 2 k-halves (L2-resident; fill covers latency) ----
        const sh8* wfp = (const sh8*)Wf + (size_t)(2 * kc * 16 + 2 * wv) * 64 + lane;
        sh8 a00 = wfp[0];          // kc16=2kc,   mf=2wv
        sh8 a01 = wfp[64];         // kc16=2kc,   mf=2wv+1
        sh8 a10 = wfp[1024];       // kc16=2kc+1, mf=2wv
        sh8 a11 = wfp[1088];       // kc16=2kc+1, mf=2wv+1

        // ---- DMA chunk kc+2 into xc[kc&1] (last read by fill(kc) one iter ago;
        //      drained by this iteration's barrier, read by fill(kc+2) next) ----
        if (kc <= 13) stage_x(kc + 2);

        // ---- fill next chunk from xc[(kc+1)&1] (landed 1+ barriers ago) ----
        if (kc <= 14) fill(kc + 1);

        // ---- MFMA on current chunk: 20 x 16x16x32_f16 per wave ----
        const __half* flr = fl[kc & 1];
        __builtin_amdgcn_s_setprio(1);
        #pragma unroll
        for (int nf = 0; nf < 5; ++nf) {
            sh8 b0 = *(const sh8*)&flr[(nf * 16 + lr) * FLS + lk];
            acc[0][nf] = __builtin_amdgcn_mfma_f32_16x16x32_f16(a00, b0, acc[0][nf], 0, 0, 0);
            acc[1][nf] = __builtin_amdgcn_mfma_f32_16x16x32_f16(a01, b0, acc[1][nf], 0, 0, 0);
            sh8 b1 = *(const sh8*)&flr[(nf * 16 + lr) * FLS + 32 + lk];
            acc[0][nf] = __builtin_amdgcn_mfma_f32_16x16x32_f16(a10, b1, acc[0][nf], 0, 0, 0);
            acc[1][nf] = __builtin_amdgcn_mfma_f32_16x16x32_f16(a11, b1, acc[1][nf], 0, 0, 0);
        }
        __builtin_amdgcn_s_setprio(0);

        __syncthreads();   // fl[(kc+1)&1] + xc[kc&1] DMA complete (sole barrier)
    }

    // ---- epilogue: bias + fp32 store ----
    float* ob = outg + (size_t)b * (COUT * NPIX) + p0;
    #pragma unroll
    for (int mi = 0; mi < 2; ++mi) {
        #pragma unroll
        for (int r = 0; r < 4; ++r) {
            int m = (wv * 2 + mi) * 16 + (lane >> 4) * 4 + r;
            float bs = biasg[m];
            #pragma unroll
            for (int nf = 0; nf < 5; ++nf)
                ob[(size_t)m * NPIX + nf * 16 + lr] = acc[mi][nf][r] + bs;
        }
    }
}

extern "C" void kernel_launch(void* const* d_in, const int* in_sizes, int n_in,
                              void* d_out, int out_size, void* d_ws, size_t ws_size,
                              hipStream_t stream) {
    const float* x    = (const float*)d_in[0];
    const float* flow = (const float*)d_in[1];
    const float* comb = (const float*)d_in[2];
    const float* bias = (const float*)d_in[3];
    float* out = (float*)d_out;

    __half* Wf = (__half*)d_ws;                          // 512 KB frag-layout f16 W
    __half* xt = (__half*)((char*)d_ws + (512 << 10));   // 6.25 MB + pad f16 x-transpose

    prep_w<<<dim3(128), dim3(256), 0, stream>>>(comb, Wf);
    prep_x<<<dim3(512), dim3(256), 0, stream>>>(x, xt);
    flow_main<<<dim3(BATCH * NPT), dim3(NTH), 0, stream>>>(xt, Wf, flow, bias, out);
}